// Round 6
// baseline (754.211 us; speedup 1.0000x reference)
//
#include <hip/hip_runtime.h>
#include <hip/hip_bf16.h>

#define N_IN_F 384
#define N_HID  128
#define N_OUT  64

typedef unsigned short ushort_t;
typedef __attribute__((ext_vector_type(8))) short short8v;   // 8 bf16 (4 VGPRs)
typedef __attribute__((ext_vector_type(4))) float floatx4;   // MFMA C/D

union U8 { uint4 v; unsigned short u[8]; };

__device__ __forceinline__ float bfu2f(unsigned short s){
    union { unsigned i; float f; } c; c.i = ((unsigned)s) << 16; return c.f;
}
__device__ __forceinline__ unsigned short f2bfu(float f){
    __hip_bfloat16 h = __float2bfloat16(f);
    union { __hip_bfloat16 h; unsigned short u; } c; c.h = h; return c.u;
}

// fm == 1: tensor is bf16; fm == 0: tensor is float32
__device__ __forceinline__ float loadS(const void* p, size_t i, int fm){
    return fm ? bfu2f(((const unsigned short*)p)[i]) : ((const float*)p)[i];
}

// ---------------- dtype probes ----------------
__global__ void k_detect_all(const int* __restrict__ ei, const unsigned* __restrict__ xw,
                             int* __restrict__ modep){
    int lane = threadIdx.x & 63;
    int zi = 0;
    if (lane < 32) zi = ei[2*lane + 1];
    int cnt = 0;
    #pragma unroll
    for (int q = 0; q < 8; q++){
        unsigned w = xw[lane*8 + q];
        unsigned elo = (w >> 7) & 0xff;
        cnt += (elo >= 118 && elo <= 134) ? 1 : 0;
    }
    #pragma unroll
    for (int m = 32; m; m >>= 1){ zi |= __shfl_xor(zi, m, 64); cnt += __shfl_xor(cnt, m, 64); }
    if (lane == 0 && blockIdx.x == 0){
        modep[0] = (zi == 0) ? 1 : 0;
        modep[1] = (cnt >= 256) ? 1 : 0;
    }
}

__device__ __forceinline__ int edge_src(const int* ei, int e, int i, int mode){
    return mode ? ei[2*(size_t)i] : ei[i];
}
__device__ __forceinline__ int edge_dst(const int* ei, int e, int i, int mode){
    return mode ? ei[2*(size_t)e + 2*(size_t)i] : ei[(size_t)e + i];
}

// ---------------- CSR build ----------------
__global__ void k_hist(const int* __restrict__ ei, int e, int n, const int* __restrict__ modep,
                       int* __restrict__ deg){
    int i = blockIdx.x * 256 + threadIdx.x;
    if (i >= e) return;
    int mode = modep[0];
    int d = edge_dst(ei, e, i, mode);
    if ((unsigned)d >= (unsigned)n) return;
    atomicAdd(&deg[d], 1);
}

__global__ __launch_bounds__(1024) void k_blksum(
    const int* __restrict__ deg, int n, int* __restrict__ part)
{
    __shared__ int s[1024];
    int i = blockIdx.x * 1024 + threadIdx.x;
    s[threadIdx.x] = (i < n) ? deg[i] : 0;
    __syncthreads();
    for (int off = 512; off; off >>= 1){
        if (threadIdx.x < off) s[threadIdx.x] += s[threadIdx.x + off];
        __syncthreads();
    }
    if (threadIdx.x == 0) part[blockIdx.x] = s[0];
}

// parallel scan of nb (<=128) partials; part becomes exclusive, rowoff[n]=total
__global__ __launch_bounds__(128) void k_scanpart(
    int* __restrict__ part, int nb, int* __restrict__ rowoff, int n)
{
    __shared__ int s[128];
    int t = threadIdx.x;
    if (nb <= 128){
        int v = (t < nb) ? part[t] : 0;
        s[t] = v; __syncthreads();
        #pragma unroll
        for (int off = 1; off < 128; off <<= 1){
            int tmp = (t >= off) ? s[t - off] : 0;
            __syncthreads();
            s[t] += tmp;
            __syncthreads();
        }
        if (t < nb) part[t] = s[t] - v;
        if (t == 127) rowoff[n] = s[127];
    } else if (t == 0){
        int run = 0;
        for (int b = 0; b < nb; b++){ int tt = part[b]; part[b] = run; run += tt; }
        rowoff[n] = run;
    }
}

__global__ __launch_bounds__(1024) void k_scanblk(
    int* __restrict__ deg, const int* __restrict__ part, int n, int* __restrict__ rowoff)
{
    __shared__ int s[1024];
    int t = threadIdx.x;
    int i = blockIdx.x * 1024 + t;
    int v = (i < n) ? deg[i] : 0;
    s[t] = v; __syncthreads();
    for (int off = 1; off < 1024; off <<= 1){
        int tmp = (t >= off) ? s[t - off] : 0;
        __syncthreads();
        s[t] += tmp;
        __syncthreads();
    }
    if (i < n){
        int excl = s[t] - v + part[blockIdx.x];
        rowoff[i] = excl;
        deg[i]    = excl;   // deg becomes the scatter cursor
    }
}

// packed scatter: one 8B store per edge (halves line-granularity write amp)
__global__ void k_scatter(const int* __restrict__ ei, const void* __restrict__ ea,
                          int e, int n, const int* __restrict__ modep,
                          int* __restrict__ cursor, int2* __restrict__ colw)
{
    int i = blockIdx.x * 256 + threadIdx.x;
    if (i >= e) return;
    int mode = modep[0], fm = modep[1];
    int d = edge_dst(ei, e, i, mode);
    if ((unsigned)d >= (unsigned)n) return;
    int s = edge_src(ei, e, i, mode);
    if ((unsigned)s >= (unsigned)n) s = 0;
    int pos = atomicAdd(&cursor[d], 1);
    if ((unsigned)pos >= (unsigned)e) return;
    int2 pk; pk.x = s; pk.y = __float_as_int(loadS(ea, i, fm));
    colw[pos] = pk;
}

// ---------------- weight prep ----------------
__global__ __launch_bounds__(64) void k_prep_w1(
    const void* __restrict__ W, const void* __restrict__ g, const void* __restrict__ b,
    const void* __restrict__ fc1b, const int* __restrict__ fmp,
    ushort_t* __restrict__ Wp, float* __restrict__ u, float* __restrict__ v)
{
    int fm = fmp[0];
    int j = blockIdx.x, lane = threadIdx.x;
    float su = 0.f, sv = 0.f;
    for (int k = lane; k < N_IN_F; k += 64){
        float w  = loadS(W, (size_t)j*N_IN_F + k, fm);
        float gk = loadS(g, k, fm);
        float bk = loadS(b, k, fm);
        unsigned short pw = f2bfu(gk * w);
        Wp[(size_t)j*N_IN_F + k] = pw;
        su += bfu2f(pw);
        sv += bk * w;
    }
    #pragma unroll
    for (int m = 32; m; m >>= 1){ su += __shfl_xor(su, m, 64); sv += __shfl_xor(sv, m, 64); }
    if (lane == 0){
        u[j] = su;
        v[j] = sv + loadS(fc1b, j, fm);
    }
}

__global__ void k_cvt4(const void* __restrict__ p0, const void* __restrict__ p1,
                       const void* __restrict__ p2, const void* __restrict__ p3,
                       const int* __restrict__ fmp, ushort_t* __restrict__ o)
{
    int fm = fmp[0];
    int i = blockIdx.x * 256 + threadIdx.x;
    if (i >= 49152) return;
    const void* p; int off;
    if (i < 16384)      { p = p0; off = i; }
    else if (i < 32768) { p = p1; off = i - 16384; }
    else if (i < 40960) { p = p2; off = i - 32768; }
    else                { p = p3; off = i - 40960; }
    o[i] = f2bfu(loadS(p, off, fm));
}

// ---------------- MFMA GEMM1 with fused LN stats ----------------
// block: 4 waves, each 16 rows x 128 cols -> 64 rows/block, grid ~1563
__global__ __launch_bounds__(256) void k_gemm1_mfma(
    const void* __restrict__ x, const int* __restrict__ fmp,
    const ushort_t* __restrict__ Wp,
    const float* __restrict__ u, const float* __restrict__ v,
    ushort_t* __restrict__ out, int n)
{
    int fm = fmp[0];
    int t = threadIdx.x;
    int wave = t >> 6, lane = t & 63;
    int r16 = lane & 15, kq = lane >> 4;
    int m0 = blockIdx.x * 64 + wave * 16;
    int rA = min(m0 + r16, n - 1);

    floatx4 acc[8];
    #pragma unroll
    for (int c = 0; c < 8; c++) acc[c] = (floatx4){0.f, 0.f, 0.f, 0.f};
    float s1 = 0.f, s2 = 0.f;

    for (int ks = 0; ks < N_IN_F/32; ks++){
        int kb = ks*32 + kq*8;
        size_t idx = (size_t)rA*N_IN_F + kb;
        short8v af;
        float f[8];
        if (fm){
            short8v sv = *(const short8v*)((const ushort_t*)x + idx);
            af = sv;
            #pragma unroll
            for (int q = 0; q < 8; q++) f[q] = bfu2f((unsigned short)sv[q]);
        } else {
            const float* xf = (const float*)x + idx;
            floatx4 p = *(const floatx4*)xf;
            floatx4 q4 = *(const floatx4*)(xf + 4);
            f[0]=p[0]; f[1]=p[1]; f[2]=p[2]; f[3]=p[3];
            f[4]=q4[0]; f[5]=q4[1]; f[6]=q4[2]; f[7]=q4[3];
            short8v r;
            #pragma unroll
            for (int q = 0; q < 8; q++) r[q] = (short)f2bfu(f[q]);
            af = r;
        }
        #pragma unroll
        for (int q = 0; q < 8; q++){ s1 += f[q]; s2 += f[q]*f[q]; }

        short8v bfr[8];
        #pragma unroll
        for (int ni = 0; ni < 8; ni++)
            bfr[ni] = *(const short8v*)(Wp + (size_t)(ni*16 + r16)*N_IN_F + kb);
        #pragma unroll
        for (int ni = 0; ni < 8; ni++)
            acc[ni] = __builtin_amdgcn_mfma_f32_16x16x32_bf16(af, bfr[ni], acc[ni], 0, 0, 0);
    }

    // stats: reduce across the 4 kq-lanes of each row
    s1 += __shfl_xor(s1, 16, 64); s1 += __shfl_xor(s1, 32, 64);
    s2 += __shfl_xor(s2, 16, 64); s2 += __shfl_xor(s2, 32, 64);
    float mu = s1 * (1.f/384.f);
    float var = fmaxf(s2 * (1.f/384.f) - mu*mu, 0.f);
    float rs = rsqrtf(var + 1e-5f);

    // epilogue: C/D layout col=r16, row=kq*4+r
    int ib = m0 + kq*4;
    float mm[4], rr[4];
    #pragma unroll
    for (int r = 0; r < 4; r++){
        mm[r] = __shfl(mu, kq*4 + r, 64);
        rr[r] = __shfl(rs, kq*4 + r, 64);
    }
    #pragma unroll
    for (int ni = 0; ni < 8; ni++){
        int j = ni*16 + r16;
        float uj = u[j], vj = v[j];
        #pragma unroll
        for (int r = 0; r < 4; r++){
            int ii = ib + r;
            float val = rr[r]*acc[ni][r] - rr[r]*mm[r]*uj + vj;
            if (ii < n) out[(size_t)ii*N_HID + j] = f2bfu(val);
        }
    }
}

// ---------------- conv1 MFMA: leaky(A1@W1^T + A2@W2^T + bias), 128 cols ----------------
__global__ __launch_bounds__(256) void k_conv1_mfma(
    const ushort_t* __restrict__ A1, const ushort_t* __restrict__ A2,
    const ushort_t* __restrict__ W1, const ushort_t* __restrict__ W2,
    const void* __restrict__ bias, const int* __restrict__ fmp,
    ushort_t* __restrict__ out, int n)
{
    int fm = fmp[0];
    int t = threadIdx.x;
    int wave = t >> 6, lane = t & 63;
    int r16 = lane & 15, kq = lane >> 4;
    int m0 = blockIdx.x * 64 + wave * 16;
    int rA = min(m0 + r16, n - 1);

    floatx4 acc[8];
    #pragma unroll
    for (int c = 0; c < 8; c++) acc[c] = (floatx4){0.f, 0.f, 0.f, 0.f};

    #pragma unroll
    for (int p = 0; p < 2; p++){
        const ushort_t* A = p ? A2 : A1;
        const ushort_t* W = p ? W2 : W1;
        #pragma unroll
        for (int ks = 0; ks < 4; ks++){
            int kb = ks*32 + kq*8;
            short8v af = *(const short8v*)(A + (size_t)rA*N_HID + kb);
            short8v bfr[8];
            #pragma unroll
            for (int ni = 0; ni < 8; ni++)
                bfr[ni] = *(const short8v*)(W + (size_t)(ni*16 + r16)*N_HID + kb);
            #pragma unroll
            for (int ni = 0; ni < 8; ni++)
                acc[ni] = __builtin_amdgcn_mfma_f32_16x16x32_bf16(af, bfr[ni], acc[ni], 0, 0, 0);
        }
    }

    int ib = m0 + kq*4;
    #pragma unroll
    for (int ni = 0; ni < 8; ni++){
        int j = ni*16 + r16;
        float bb = loadS(bias, j, fm);
        #pragma unroll
        for (int r = 0; r < 4; r++){
            int ii = ib + r;
            float val = acc[ni][r] + bb;
            val = (val >= 0.f) ? val : 0.01f * val;
            if (ii < n) out[(size_t)ii*N_HID + j] = f2bfu(val);
        }
    }
}

// ---------------- conv2 + LN2 + fc2 fused ----------------
// wave: 16 rows x 64 cols. Row ii's 64 outputs live in its 16-lane group (x 4 regs).
__global__ __launch_bounds__(256) void k_conv2_final(
    const ushort_t* __restrict__ A1, const ushort_t* __restrict__ A2,
    const ushort_t* __restrict__ W1, const ushort_t* __restrict__ W2,
    const void* __restrict__ bias,
    const void* __restrict__ gam, const void* __restrict__ bet,
    const void* __restrict__ Wfc, const void* __restrict__ bfc,
    const int* __restrict__ fmp, void* __restrict__ out, int n)
{
    int fm = fmp[0];
    int t = threadIdx.x;
    int wave = t >> 6, lane = t & 63;
    int r16 = lane & 15, kq = lane >> 4;
    int m0 = blockIdx.x * 64 + wave * 16;
    int rA = min(m0 + r16, n - 1);

    floatx4 acc[4];
    #pragma unroll
    for (int c = 0; c < 4; c++) acc[c] = (floatx4){0.f, 0.f, 0.f, 0.f};

    #pragma unroll
    for (int p = 0; p < 2; p++){
        const ushort_t* A = p ? A2 : A1;
        const ushort_t* W = p ? W2 : W1;
        #pragma unroll
        for (int ks = 0; ks < 4; ks++){
            int kb = ks*32 + kq*8;
            short8v af = *(const short8v*)(A + (size_t)rA*N_HID + kb);
            short8v bfr[4];
            #pragma unroll
            for (int ni = 0; ni < 4; ni++)
                bfr[ni] = *(const short8v*)(W + (size_t)(ni*16 + r16)*N_HID + kb);
            #pragma unroll
            for (int ni = 0; ni < 4; ni++)
                acc[ni] = __builtin_amdgcn_mfma_f32_16x16x32_bf16(af, bfr[ni], acc[ni], 0, 0, 0);
        }
    }

    // leaky-relu + per-row LN stats (row = m0 + kq*4 + r; 64 cols over 16 lanes x 4 regs)
    float s[4] = {}, s2[4] = {};
    #pragma unroll
    for (int ni = 0; ni < 4; ni++){
        int j = ni*16 + r16;
        float bb = loadS(bias, j, fm);
        #pragma unroll
        for (int r = 0; r < 4; r++){
            float val = acc[ni][r] + bb;
            val = (val >= 0.f) ? val : 0.01f * val;
            acc[ni][r] = val;
            s[r] += val; s2[r] += val*val;
        }
    }
    #pragma unroll
    for (int m = 1; m < 16; m <<= 1){
        #pragma unroll
        for (int r = 0; r < 4; r++){
            s[r]  += __shfl_xor(s[r],  m, 64);
            s2[r] += __shfl_xor(s2[r], m, 64);
        }
    }
    float mu[4], rstd[4];
    #pragma unroll
    for (int r = 0; r < 4; r++){
        mu[r] = s[r] * (1.f/64.f);
        float var = fmaxf(s2[r] * (1.f/64.f) - mu[r]*mu[r], 0.f);
        rstd[r] = rsqrtf(var + 1e-5f);
    }
    // LN2 affine + fc2 (64 -> 2), reduce over the 16-lane group
    float p0[4] = {}, p1[4] = {};
    #pragma unroll
    for (int ni = 0; ni < 4; ni++){
        int j = ni*16 + r16;
        float gj = loadS(gam, j, fm), bj = loadS(bet, j, fm);
        float w0 = loadS(Wfc, j, fm), w1 = loadS(Wfc, 64 + j, fm);
        #pragma unroll
        for (int r = 0; r < 4; r++){
            float zn = (acc[ni][r] - mu[r]) * rstd[r] * gj + bj;
            p0[r] += zn * w0;
            p1[r] += zn * w1;
        }
    }
    #pragma unroll
    for (int m = 1; m < 16; m <<= 1){
        #pragma unroll
        for (int r = 0; r < 4; r++){
            p0[r] += __shfl_xor(p0[r], m, 64);
            p1[r] += __shfl_xor(p1[r], m, 64);
        }
    }
    if (r16 == 0){
        float b0 = loadS(bfc, 0, fm), b1 = loadS(bfc, 1, fm);
        #pragma unroll
        for (int r = 0; r < 4; r++){
            int ii = m0 + kq*4 + r;
            if (ii >= n) continue;
            float o0 = p0[r] + b0, o1 = p1[r] + b1;
            if (fm){
                unsigned pk = ((unsigned)f2bfu(o1) << 16) | (unsigned)f2bfu(o0);
                *(unsigned*)((ushort_t*)out + (size_t)ii*2) = pk;
            } else {
                float2 f2; f2.x = o0; f2.y = o1;
                *(float2*)((float*)out + (size_t)ii*2) = f2;
            }
        }
    }
}

// ---------------- CSR aggregation: 4-edge MLP, 16B row loads, packed colw ----------------
__global__ __launch_bounds__(256) void k_agg(
    const int* __restrict__ rowoff, const int2* __restrict__ colw,
    const ushort_t* __restrict__ src_mat,   // [n,128] bf16
    ushort_t* __restrict__ out, int n, int eTot)
{
    int t = threadIdx.x;
    int lane = t & 63;
    int d = blockIdx.x * 4 + (t >> 6);
    if (d >= n) return;
    int grp = lane >> 4;     // 0..3: edge interleave
    int c16 = lane & 15;     // 16B column segment (8 bf16)
    int e0 = rowoff[d], e1 = rowoff[d+1];
    e0 = max(0, min(e0, eTot));
    e1 = max(e0, min(e1, eTot));
    float acc[8] = {};
    for (int e = e0 + grp; e < e1; e += 4){
        int2 cw = colw[e];
        int s = cw.x;
        if ((unsigned)s >= (unsigned)n) s = 0;
        float wv = __int_as_float(cw.y);
        U8 u; u.v = *(const uint4*)(src_mat + (size_t)s*N_HID + c16*8);
        #pragma unroll
        for (int q = 0; q < 8; q++) acc[q] += wv * bfu2f(u.u[q]);
    }
    #pragma unroll
    for (int q = 0; q < 8; q++){
        acc[q] += __shfl_xor(acc[q], 16, 64);
        acc[q] += __shfl_xor(acc[q], 32, 64);
    }
    if (grp == 0){
        union { ushort_t u[8]; uint4 v; } P;
        #pragma unroll
        for (int q = 0; q < 8; q++) P.u[q] = f2bfu(acc[q]);
        *(uint4*)(out + (size_t)d*N_HID + c16*8) = P.v;
    }
}

// ---------------- launch ----------------
extern "C" void kernel_launch(void* const* d_in, const int* in_sizes, int n_in,
                              void* d_out, int out_size, void* d_ws, size_t ws_size,
                              hipStream_t stream)
{
    const void* x     = d_in[0];
    const int*  ei    = (const int*)d_in[1];
    const void* ea    = d_in[2];
    const void* ln1g  = d_in[3];
    const void* ln1b  = d_in[4];
    const void* fc1w  = d_in[5];
    const void* fc1b  = d_in[6];
    const void* c1rel = d_in[7];
    const void* c1bre = d_in[8];
    const void* c1roo = d_in[9];
    const void* c2rel = d_in[10];
    const void* c2bre = d_in[11];
    const void* c2roo = d_in[12];
    const void* ln2g  = d_in[13];
    const void* ln2b  = d_in[14];
    const void* fc2w  = d_in[15];
    const void* fc2b  = d_in[16];
    (void)n_in; (void)out_size; (void)ws_size;

    const int n = in_sizes[0] / N_IN_F;
    const int e = in_sizes[2];

    char* wsp = (char*)d_ws;
    size_t off = 0;
    auto alloc = [&](size_t bytes) -> char* {
        char* p = wsp + off; off += (bytes + 255) & ~(size_t)255; return p;
    };
    int*      deg    = (int*)  alloc((size_t)n * 4);        // becomes cursor
    int*      rowoff = (int*)  alloc((size_t)(n+1) * 4);
    int*      part   = (int*)  alloc(4096);
    int*      modep  = (int*)  alloc(256);
    int2*     colw   = (int2*) alloc((size_t)e * 8);
    float*    u      = (float*)alloc(128 * 4);
    float*    v      = (float*)alloc(128 * 4);
    ushort_t* Wp     = (ushort_t*)alloc((size_t)N_HID * N_IN_F * 2);
    ushort_t* cw     = (ushort_t*)alloc((size_t)49152 * 2);
    ushort_t* h1     = (ushort_t*)alloc((size_t)n * N_HID * 2);
    ushort_t* agg1   = (ushort_t*)alloc((size_t)n * N_HID * 2);
    ushort_t* g1     = (ushort_t*)alloc((size_t)n * N_HID * 2);
    ushort_t* agg2   = h1;    // h1 dead after conv1 GEMM

    hipMemsetAsync(deg, 0, (size_t)n * 4, stream);
    k_detect_all<<<1, 64, 0, stream>>>(ei, (const unsigned*)x, modep);

    int nb = (n + 1023) / 1024;
    k_hist    <<<(e + 255) / 256, 256, 0, stream>>>(ei, e, n, modep, deg);
    k_blksum  <<<nb, 1024, 0, stream>>>(deg, n, part);
    k_scanpart<<<1, 128, 0, stream>>>(part, nb, rowoff, n);
    k_scanblk <<<nb, 1024, 0, stream>>>(deg, part, n, rowoff);
    k_scatter <<<(e + 255) / 256, 256, 0, stream>>>(ei, ea, e, n, modep, deg, colw);

    k_prep_w1<<<N_HID, 64, 0, stream>>>(fc1w, ln1g, ln1b, fc1b, modep + 1, Wp, u, v);
    k_cvt4   <<<(49152 + 255) / 256, 256, 0, stream>>>(c1rel, c1roo, c2rel, c2roo, modep + 1, cw);

    k_gemm1_mfma<<<(n + 63) / 64, 256, 0, stream>>>(x, modep + 1, Wp, u, v, h1, n);

    k_agg<<<(n + 3) / 4, 256, 0, stream>>>(rowoff, colw, h1, agg1, n, e);
    k_conv1_mfma<<<(n + 63) / 64, 256, 0, stream>>>(agg1, h1, cw, cw + 16384, c1bre, modep + 1, g1, n);

    k_agg<<<(n + 3) / 4, 256, 0, stream>>>(rowoff, colw, g1, agg2, n, e);
    k_conv2_final<<<(n + 63) / 64, 256, 0, stream>>>(agg2, g1, cw + 32768, cw + 40960, c2bre,
                                                     ln2g, ln2b, fc2w, fc2b, modep + 1, d_out, n);
}

// Round 7
// 673.783 us; speedup vs baseline: 1.1194x; 1.1194x over previous
//
#include <hip/hip_runtime.h>
#include <hip/hip_bf16.h>

#define N_IN_F 384
#define N_HID  128
#define N_OUT  64

typedef unsigned short ushort_t;
typedef __attribute__((ext_vector_type(8))) short short8v;   // 8 bf16 (4 VGPRs)
typedef __attribute__((ext_vector_type(4))) float floatx4;   // MFMA C/D

union U8 { uint4 v; unsigned short u[8]; };

__device__ __forceinline__ float bfu2f(unsigned short s){
    union { unsigned i; float f; } c; c.i = ((unsigned)s) << 16; return c.f;
}
__device__ __forceinline__ unsigned short f2bfu(float f){
    __hip_bfloat16 h = __float2bfloat16(f);
    union { __hip_bfloat16 h; unsigned short u; } c; c.h = h; return c.u;
}

// fm == 1: tensor is bf16; fm == 0: tensor is float32
__device__ __forceinline__ float loadS(const void* p, size_t i, int fm){
    return fm ? bfu2f(((const unsigned short*)p)[i]) : ((const float*)p)[i];
}

// ---------------- dtype probes ----------------
__global__ void k_detect_all(const int* __restrict__ ei, const unsigned* __restrict__ xw,
                             int* __restrict__ modep){
    int lane = threadIdx.x & 63;
    int zi = 0;
    if (lane < 32) zi = ei[2*lane + 1];
    int cnt = 0;
    #pragma unroll
    for (int q = 0; q < 8; q++){
        unsigned w = xw[lane*8 + q];
        unsigned elo = (w >> 7) & 0xff;
        cnt += (elo >= 118 && elo <= 134) ? 1 : 0;
    }
    #pragma unroll
    for (int m = 32; m; m >>= 1){ zi |= __shfl_xor(zi, m, 64); cnt += __shfl_xor(cnt, m, 64); }
    if (lane == 0 && blockIdx.x == 0){
        modep[0] = (zi == 0) ? 1 : 0;
        modep[1] = (cnt >= 256) ? 1 : 0;
    }
}

__device__ __forceinline__ int edge_src(const int* ei, int e, int i, int mode){
    return mode ? ei[2*(size_t)i] : ei[i];
}
__device__ __forceinline__ int edge_dst(const int* ei, int e, int i, int mode){
    return mode ? ei[2*(size_t)e + 2*(size_t)i] : ei[(size_t)e + i];
}

// ---------------- CSR build ----------------
__global__ void k_hist(const int* __restrict__ ei, int e, int n, const int* __restrict__ modep,
                       int* __restrict__ deg){
    int i = blockIdx.x * 256 + threadIdx.x;
    if (i >= e) return;
    int mode = modep[0];
    int d = edge_dst(ei, e, i, mode);
    if ((unsigned)d >= (unsigned)n) return;
    atomicAdd(&deg[d], 1);
}

__global__ __launch_bounds__(1024) void k_blksum(
    const int* __restrict__ deg, int n, int* __restrict__ part)
{
    __shared__ int s[1024];
    int i = blockIdx.x * 1024 + threadIdx.x;
    s[threadIdx.x] = (i < n) ? deg[i] : 0;
    __syncthreads();
    for (int off = 512; off; off >>= 1){
        if (threadIdx.x < off) s[threadIdx.x] += s[threadIdx.x + off];
        __syncthreads();
    }
    if (threadIdx.x == 0) part[blockIdx.x] = s[0];
}

__global__ __launch_bounds__(128) void k_scanpart(
    int* __restrict__ part, int nb, int* __restrict__ rowoff, int n)
{
    __shared__ int s[128];
    int t = threadIdx.x;
    if (nb <= 128){
        int v = (t < nb) ? part[t] : 0;
        s[t] = v; __syncthreads();
        #pragma unroll
        for (int off = 1; off < 128; off <<= 1){
            int tmp = (t >= off) ? s[t - off] : 0;
            __syncthreads();
            s[t] += tmp;
            __syncthreads();
        }
        if (t < nb) part[t] = s[t] - v;
        if (t == 127) rowoff[n] = s[127];
    } else if (t == 0){
        int run = 0;
        for (int b = 0; b < nb; b++){ int tt = part[b]; part[b] = run; run += tt; }
        rowoff[n] = run;
    }
}

__global__ __launch_bounds__(1024) void k_scanblk(
    int* __restrict__ deg, const int* __restrict__ part, int n, int* __restrict__ rowoff)
{
    __shared__ int s[1024];
    int t = threadIdx.x;
    int i = blockIdx.x * 1024 + t;
    int v = (i < n) ? deg[i] : 0;
    s[t] = v; __syncthreads();
    for (int off = 1; off < 1024; off <<= 1){
        int tmp = (t >= off) ? s[t - off] : 0;
        __syncthreads();
        s[t] += tmp;
        __syncthreads();
    }
    if (i < n){
        int excl = s[t] - v + part[blockIdx.x];
        rowoff[i] = excl;
        deg[i]    = excl;   // deg becomes the scatter cursor
    }
}

// packed scatter: one 8B store per edge
__global__ void k_scatter(const int* __restrict__ ei, const void* __restrict__ ea,
                          int e, int n, const int* __restrict__ modep,
                          int* __restrict__ cursor, int2* __restrict__ colw)
{
    int i = blockIdx.x * 256 + threadIdx.x;
    if (i >= e) return;
    int mode = modep[0], fm = modep[1];
    int d = edge_dst(ei, e, i, mode);
    if ((unsigned)d >= (unsigned)n) return;
    int s = edge_src(ei, e, i, mode);
    if ((unsigned)s >= (unsigned)n) s = 0;
    int pos = atomicAdd(&cursor[d], 1);
    if ((unsigned)pos >= (unsigned)e) return;
    int2 pk; pk.x = s; pk.y = __float_as_int(loadS(ea, i, fm));
    colw[pos] = pk;
}

// ---------------- weight prep ----------------
__global__ __launch_bounds__(64) void k_prep_w1(
    const void* __restrict__ W, const void* __restrict__ g, const void* __restrict__ b,
    const void* __restrict__ fc1b, const int* __restrict__ fmp,
    ushort_t* __restrict__ Wp, float* __restrict__ u, float* __restrict__ v)
{
    int fm = fmp[0];
    int j = blockIdx.x, lane = threadIdx.x;
    float su = 0.f, sv = 0.f;
    for (int k = lane; k < N_IN_F; k += 64){
        float w  = loadS(W, (size_t)j*N_IN_F + k, fm);
        float gk = loadS(g, k, fm);
        float bk = loadS(b, k, fm);
        unsigned short pw = f2bfu(gk * w);
        Wp[(size_t)j*N_IN_F + k] = pw;
        su += bfu2f(pw);
        sv += bk * w;
    }
    #pragma unroll
    for (int m = 32; m; m >>= 1){ su += __shfl_xor(su, m, 64); sv += __shfl_xor(sv, m, 64); }
    if (lane == 0){
        u[j] = su;
        v[j] = sv + loadS(fc1b, j, fm);
    }
}

__global__ void k_cvt4(const void* __restrict__ p0, const void* __restrict__ p1,
                       const void* __restrict__ p2, const void* __restrict__ p3,
                       const int* __restrict__ fmp, ushort_t* __restrict__ o)
{
    int fm = fmp[0];
    int i = blockIdx.x * 256 + threadIdx.x;
    if (i >= 49152) return;
    const void* p; int off;
    if (i < 16384)      { p = p0; off = i; }
    else if (i < 32768) { p = p1; off = i - 16384; }
    else if (i < 40960) { p = p2; off = i - 32768; }
    else                { p = p3; off = i - 40960; }
    o[i] = f2bfu(loadS(p, off, fm));
}

// ================= LDS-staged MFMA GEMM1 (fused LN1) =================
// block tile 128x128, 4 waves x (32 rows x 128 cols), BK=32, K=384.
// LDS pitch 40 ushorts (80B) -> 16B-aligned b128 reads, 2-way conflicts max.
__global__ __launch_bounds__(256) void k_gemm1_mfma(
    const void* __restrict__ x, const int* __restrict__ fmp,
    const ushort_t* __restrict__ Wp,
    const float* __restrict__ u, const float* __restrict__ v,
    ushort_t* __restrict__ out, int n)
{
    __shared__ ushort_t As[128*40];
    __shared__ ushort_t Bs[128*40];
    int fm = fmp[0];
    int t = threadIdx.x;
    int wave = t >> 6, lane = t & 63;
    int r16 = lane & 15, kq = lane >> 4;
    int m0 = blockIdx.x * 128;
    int mw = m0 + wave * 32;

    // staging indices
    int sq = t & 3, srow = t >> 2;       // A: quarter-row (8 elems), rows srow, srow+64
    int bcol = t & 127, bhalf = t >> 7;  // B: col, 16-elem half

    floatx4 acc[2][8];
    #pragma unroll
    for (int a = 0; a < 2; a++)
        #pragma unroll
        for (int c = 0; c < 8; c++) acc[a][c] = (floatx4){0.f,0.f,0.f,0.f};
    float s1[2] = {0.f,0.f}, s2[2] = {0.f,0.f};

    for (int ks = 0; ks < 12; ks++){
        int kb = ks*32;
        // ---- stage A (coalesced, cvt to bf16) ----
        #pragma unroll
        for (int pass = 0; pass < 2; pass++){
            int row  = srow + pass*64;
            int grow = min(m0 + row, n - 1);
            union { ushort_t u[8]; uint4 v4; } w;
            if (fm){
                w.v4 = *(const uint4*)((const ushort_t*)x + (size_t)grow*N_IN_F + kb + sq*8);
            } else {
                const float* xf = (const float*)x + (size_t)grow*N_IN_F + kb + sq*8;
                floatx4 p = *(const floatx4*)xf;
                floatx4 q4 = *(const floatx4*)(xf + 4);
                w.u[0]=f2bfu(p[0]); w.u[1]=f2bfu(p[1]); w.u[2]=f2bfu(p[2]); w.u[3]=f2bfu(p[3]);
                w.u[4]=f2bfu(q4[0]); w.u[5]=f2bfu(q4[1]); w.u[6]=f2bfu(q4[2]); w.u[7]=f2bfu(q4[3]);
            }
            *(uint4*)(As + row*40 + sq*8) = w.v4;
        }
        // ---- stage B (Wp always bf16) ----
        {
            const ushort_t* wp = Wp + (size_t)bcol*N_IN_F + kb + bhalf*16;
            uint4 b0 = *(const uint4*)wp;
            uint4 b1 = *(const uint4*)(wp + 8);
            *(uint4*)(Bs + bcol*40 + bhalf*16)     = b0;
            *(uint4*)(Bs + bcol*40 + bhalf*16 + 8) = b1;
        }
        __syncthreads();
        // ---- consume ----
        short8v af[2], bfr[8];
        #pragma unroll
        for (int mi = 0; mi < 2; mi++)
            af[mi] = *(const short8v*)(As + (wave*32 + mi*16 + r16)*40 + kq*8);
        #pragma unroll
        for (int ni = 0; ni < 8; ni++)
            bfr[ni] = *(const short8v*)(Bs + (ni*16 + r16)*40 + kq*8);
        #pragma unroll
        for (int mi = 0; mi < 2; mi++){
            #pragma unroll
            for (int q = 0; q < 8; q++){
                float f = bfu2f((unsigned short)af[mi][q]);
                s1[mi] += f; s2[mi] += f*f;
            }
            #pragma unroll
            for (int ni = 0; ni < 8; ni++)
                acc[mi][ni] = __builtin_amdgcn_mfma_f32_16x16x32_bf16(af[mi], bfr[ni], acc[mi][ni], 0, 0, 0);
        }
        __syncthreads();
    }

    // ---- LN stats: reduce over the 4 kq-lanes of each row ----
    float mu[2], rs[2];
    #pragma unroll
    for (int mi = 0; mi < 2; mi++){
        s1[mi] += __shfl_xor(s1[mi], 16, 64); s1[mi] += __shfl_xor(s1[mi], 32, 64);
        s2[mi] += __shfl_xor(s2[mi], 16, 64); s2[mi] += __shfl_xor(s2[mi], 32, 64);
        mu[mi] = s1[mi] * (1.f/384.f);
        float var = fmaxf(s2[mi] * (1.f/384.f) - mu[mi]*mu[mi], 0.f);
        rs[mi] = rsqrtf(var + 1e-5f);
    }

    // ---- epilogue: C/D col=r16, row=kq*4+r ----
    #pragma unroll
    for (int mi = 0; mi < 2; mi++){
        int ib = mw + mi*16 + kq*4;
        float mm[4], rr[4];
        #pragma unroll
        for (int r = 0; r < 4; r++){
            mm[r] = __shfl(mu[mi], kq*4 + r, 64);
            rr[r] = __shfl(rs[mi], kq*4 + r, 64);
        }
        #pragma unroll
        for (int ni = 0; ni < 8; ni++){
            int j = ni*16 + r16;
            float uj = u[j], vj = v[j];
            #pragma unroll
            for (int r = 0; r < 4; r++){
                int ii = ib + r;
                float val = rr[r]*acc[mi][ni][r] - rr[r]*mm[r]*uj + vj;
                if (ii < n) out[(size_t)ii*N_HID + j] = f2bfu(val);
            }
        }
    }
}

// ================= LDS-staged conv1: leaky(A1@W1^T + A2@W2^T + b) =================
// K = 256 (A1|A2 concat). Same tile structure as gemm1.
__global__ __launch_bounds__(256) void k_conv1_mfma(
    const ushort_t* __restrict__ A1, const ushort_t* __restrict__ A2,
    const ushort_t* __restrict__ W1, const ushort_t* __restrict__ W2,
    const void* __restrict__ bias, const int* __restrict__ fmp,
    ushort_t* __restrict__ out, int n)
{
    __shared__ ushort_t As[128*40];
    __shared__ ushort_t Bs[128*40];
    int fm = fmp[0];
    int t = threadIdx.x;
    int wave = t >> 6, lane = t & 63;
    int r16 = lane & 15, kq = lane >> 4;
    int m0 = blockIdx.x * 128;
    int mw = m0 + wave * 32;

    int sq = t & 3, srow = t >> 2;
    int bcol = t & 127, bhalf = t >> 7;

    floatx4 acc[2][8];
    #pragma unroll
    for (int a = 0; a < 2; a++)
        #pragma unroll
        for (int c = 0; c < 8; c++) acc[a][c] = (floatx4){0.f,0.f,0.f,0.f};

    #pragma unroll
    for (int ks = 0; ks < 8; ks++){
        const ushort_t* Asrc = (ks < 4) ? A1 : A2;
        const ushort_t* Wsrc = (ks < 4) ? W1 : W2;
        int kb = (ks & 3)*32;
        #pragma unroll
        for (int pass = 0; pass < 2; pass++){
            int row  = srow + pass*64;
            int grow = min(m0 + row, n - 1);
            uint4 w = *(const uint4*)(Asrc + (size_t)grow*N_HID + kb + sq*8);
            *(uint4*)(As + row*40 + sq*8) = w;
        }
        {
            const ushort_t* wp = Wsrc + (size_t)bcol*N_HID + kb + bhalf*16;
            uint4 b0 = *(const uint4*)wp;
            uint4 b1 = *(const uint4*)(wp + 8);
            *(uint4*)(Bs + bcol*40 + bhalf*16)     = b0;
            *(uint4*)(Bs + bcol*40 + bhalf*16 + 8) = b1;
        }
        __syncthreads();
        short8v af[2], bfr[8];
        #pragma unroll
        for (int mi = 0; mi < 2; mi++)
            af[mi] = *(const short8v*)(As + (wave*32 + mi*16 + r16)*40 + kq*8);
        #pragma unroll
        for (int ni = 0; ni < 8; ni++)
            bfr[ni] = *(const short8v*)(Bs + (ni*16 + r16)*40 + kq*8);
        #pragma unroll
        for (int mi = 0; mi < 2; mi++)
            #pragma unroll
            for (int ni = 0; ni < 8; ni++)
                acc[mi][ni] = __builtin_amdgcn_mfma_f32_16x16x32_bf16(af[mi], bfr[ni], acc[mi][ni], 0, 0, 0);
        __syncthreads();
    }

    #pragma unroll
    for (int mi = 0; mi < 2; mi++){
        int ib = mw + mi*16 + kq*4;
        #pragma unroll
        for (int ni = 0; ni < 8; ni++){
            int j = ni*16 + r16;
            float bb = loadS(bias, j, fm);
            #pragma unroll
            for (int r = 0; r < 4; r++){
                int ii = ib + r;
                float val = acc[mi][ni][r] + bb;
                val = (val >= 0.f) ? val : 0.01f * val;
                if (ii < n) out[(size_t)ii*N_HID + j] = f2bfu(val);
            }
        }
    }
}

// ================= LDS-staged conv2 + LN2 + fc2 fused =================
// tile 128 rows x 64 cols; 4 waves x (32 rows x 64 cols); K = 256.
__global__ __launch_bounds__(256) void k_conv2_final(
    const ushort_t* __restrict__ A1, const ushort_t* __restrict__ A2,
    const ushort_t* __restrict__ W1, const ushort_t* __restrict__ W2,
    const void* __restrict__ bias,
    const void* __restrict__ gam, const void* __restrict__ bet,
    const void* __restrict__ Wfc, const void* __restrict__ bfc,
    const int* __restrict__ fmp, void* __restrict__ out, int n)
{
    __shared__ ushort_t As[128*40];
    __shared__ ushort_t Bs[64*40];
    int fm = fmp[0];
    int t = threadIdx.x;
    int wave = t >> 6, lane = t & 63;
    int r16 = lane & 15, kq = lane >> 4;
    int m0 = blockIdx.x * 128;
    int mw = m0 + wave * 32;

    int sq = t & 3, srow = t >> 2;
    int bcol = t & 63, bseg = t >> 6;   // 64 cols x 4 segs of 8 elems

    floatx4 acc[2][4];
    #pragma unroll
    for (int a = 0; a < 2; a++)
        #pragma unroll
        for (int c = 0; c < 4; c++) acc[a][c] = (floatx4){0.f,0.f,0.f,0.f};

    #pragma unroll
    for (int ks = 0; ks < 8; ks++){
        const ushort_t* Asrc = (ks < 4) ? A1 : A2;
        const ushort_t* Wsrc = (ks < 4) ? W1 : W2;
        int kb = (ks & 3)*32;
        #pragma unroll
        for (int pass = 0; pass < 2; pass++){
            int row  = srow + pass*64;
            int grow = min(m0 + row, n - 1);
            uint4 w = *(const uint4*)(Asrc + (size_t)grow*N_HID + kb + sq*8);
            *(uint4*)(As + row*40 + sq*8) = w;
        }
        {
            uint4 b0 = *(const uint4*)(Wsrc + (size_t)bcol*N_HID + kb + bseg*8);
            *(uint4*)(Bs + bcol*40 + bseg*8) = b0;
        }
        __syncthreads();
        short8v af[2], bfr[4];
        #pragma unroll
        for (int mi = 0; mi < 2; mi++)
            af[mi] = *(const short8v*)(As + (wave*32 + mi*16 + r16)*40 + kq*8);
        #pragma unroll
        for (int ni = 0; ni < 4; ni++)
            bfr[ni] = *(const short8v*)(Bs + (ni*16 + r16)*40 + kq*8);
        #pragma unroll
        for (int mi = 0; mi < 2; mi++)
            #pragma unroll
            for (int ni = 0; ni < 4; ni++)
                acc[mi][ni] = __builtin_amdgcn_mfma_f32_16x16x32_bf16(af[mi], bfr[ni], acc[mi][ni], 0, 0, 0);
        __syncthreads();
    }

    float b0 = loadS(bfc, 0, fm), b1 = loadS(bfc, 1, fm);
    #pragma unroll
    for (int mi = 0; mi < 2; mi++){
        // leaky + LN stats: row = mw + mi*16 + kq*4 + r; 64 cols over 16 lanes x 4 regs
        float s[4] = {}, s2[4] = {};
        #pragma unroll
        for (int ni = 0; ni < 4; ni++){
            int j = ni*16 + r16;
            float bb = loadS(bias, j, fm);
            #pragma unroll
            for (int r = 0; r < 4; r++){
                float val = acc[mi][ni][r] + bb;
                val = (val >= 0.f) ? val : 0.01f * val;
                acc[mi][ni][r] = val;
                s[r] += val; s2[r] += val*val;
            }
        }
        #pragma unroll
        for (int m = 1; m < 16; m <<= 1){
            #pragma unroll
            for (int r = 0; r < 4; r++){
                s[r]  += __shfl_xor(s[r],  m, 64);
                s2[r] += __shfl_xor(s2[r], m, 64);
            }
        }
        float mu[4], rstd[4];
        #pragma unroll
        for (int r = 0; r < 4; r++){
            mu[r] = s[r] * (1.f/64.f);
            float var = fmaxf(s2[r] * (1.f/64.f) - mu[r]*mu[r], 0.f);
            rstd[r] = rsqrtf(var + 1e-5f);
        }
        float p0[4] = {}, p1[4] = {};
        #pragma unroll
        for (int ni = 0; ni < 4; ni++){
            int j = ni*16 + r16;
            float gj = loadS(gam, j, fm), bj = loadS(bet, j, fm);
            float w0 = loadS(Wfc, j, fm), w1 = loadS(Wfc, 64 + j, fm);
            #pragma unroll
            for (int r = 0; r < 4; r++){
                float zn = (acc[mi][ni][r] - mu[r]) * rstd[r] * gj + bj;
                p0[r] += zn * w0;
                p1[r] += zn * w1;
            }
        }
        #pragma unroll
        for (int m = 1; m < 16; m <<= 1){
            #pragma unroll
            for (int r = 0; r < 4; r++){
                p0[r] += __shfl_xor(p0[r], m, 64);
                p1[r] += __shfl_xor(p1[r], m, 64);
            }
        }
        if (r16 == 0){
            #pragma unroll
            for (int r = 0; r < 4; r++){
                int ii = mw + mi*16 + kq*4 + r;
                if (ii >= n) continue;
                float o0 = p0[r] + b0, o1 = p1[r] + b1;
                if (fm){
                    unsigned pk = ((unsigned)f2bfu(o1) << 16) | (unsigned)f2bfu(o0);
                    *(unsigned*)((ushort_t*)out + (size_t)ii*2) = pk;
                } else {
                    float2 f2; f2.x = o0; f2.y = o1;
                    *(float2*)((float*)out + (size_t)ii*2) = f2;
                }
            }
        }
    }
}

// ---------------- CSR aggregation: 4-edge MLP, 16B row loads ----------------
__global__ __launch_bounds__(256) void k_agg(
    const int* __restrict__ rowoff, const int2* __restrict__ colw,
    const ushort_t* __restrict__ src_mat,   // [n,128] bf16
    ushort_t* __restrict__ out, int n, int eTot)
{
    int t = threadIdx.x;
    int lane = t & 63;
    int d = blockIdx.x * 4 + (t >> 6);
    if (d >= n) return;
    int grp = lane >> 4;
    int c16 = lane & 15;
    int e0 = rowoff[d], e1 = rowoff[d+1];
    e0 = max(0, min(e0, eTot));
    e1 = max(e0, min(e1, eTot));
    float acc[8] = {};
    for (int e = e0 + grp; e < e1; e += 4){
        int2 cw = colw[e];
        int s = cw.x;
        if ((unsigned)s >= (unsigned)n) s = 0;
        float wv = __int_as_float(cw.y);
        U8 u; u.v = *(const uint4*)(src_mat + (size_t)s*N_HID + c16*8);
        #pragma unroll
        for (int q = 0; q < 8; q++) acc[q] += wv * bfu2f(u.u[q]);
    }
    #pragma unroll
    for (int q = 0; q < 8; q++){
        acc[q] += __shfl_xor(acc[q], 16, 64);
        acc[q] += __shfl_xor(acc[q], 32, 64);
    }
    if (grp == 0){
        union { ushort_t u[8]; uint4 v; } P;
        #pragma unroll
        for (int q = 0; q < 8; q++) P.u[q] = f2bfu(acc[q]);
        *(uint4*)(out + (size_t)d*N_HID + c16*8) = P.v;
    }
}

// ---------------- launch ----------------
extern "C" void kernel_launch(void* const* d_in, const int* in_sizes, int n_in,
                              void* d_out, int out_size, void* d_ws, size_t ws_size,
                              hipStream_t stream)
{
    const void* x     = d_in[0];
    const int*  ei    = (const int*)d_in[1];
    const void* ea    = d_in[2];
    const void* ln1g  = d_in[3];
    const void* ln1b  = d_in[4];
    const void* fc1w  = d_in[5];
    const void* fc1b  = d_in[6];
    const void* c1rel = d_in[7];
    const void* c1bre = d_in[8];
    const void* c1roo = d_in[9];
    const void* c2rel = d_in[10];
    const void* c2bre = d_in[11];
    const void* c2roo = d_in[12];
    const void* ln2g  = d_in[13];
    const void* ln2b  = d_in[14];
    const void* fc2w  = d_in[15];
    const void* fc2b  = d_in[16];
    (void)n_in; (void)out_size; (void)ws_size;

    const int n = in_sizes[0] / N_IN_F;
    const int e = in_sizes[2];

    char* wsp = (char*)d_ws;
    size_t off = 0;
    auto alloc = [&](size_t bytes) -> char* {
        char* p = wsp + off; off += (bytes + 255) & ~(size_t)255; return p;
    };
    int*      deg    = (int*)  alloc((size_t)n * 4);        // becomes cursor
    int*      rowoff = (int*)  alloc((size_t)(n+1) * 4);
    int*      part   = (int*)  alloc(4096);
    int*      modep  = (int*)  alloc(256);
    int2*     colw   = (int2*) alloc((size_t)e * 8);
    float*    u      = (float*)alloc(128 * 4);
    float*    v      = (float*)alloc(128 * 4);
    ushort_t* Wp     = (ushort_t*)alloc((size_t)N_HID * N_IN_F * 2);
    ushort_t* cw     = (ushort_t*)alloc((size_t)49152 * 2);
    ushort_t* h1     = (ushort_t*)alloc((size_t)n * N_HID * 2);
    ushort_t* agg1   = (ushort_t*)alloc((size_t)n * N_HID * 2);
    ushort_t* g1     = (ushort_t*)alloc((size_t)n * N_HID * 2);
    ushort_t* agg2   = h1;    // h1 dead after conv1 GEMM

    hipMemsetAsync(deg, 0, (size_t)n * 4, stream);
    k_detect_all<<<1, 64, 0, stream>>>(ei, (const unsigned*)x, modep);

    int nb = (n + 1023) / 1024;
    k_hist    <<<(e + 255) / 256, 256, 0, stream>>>(ei, e, n, modep, deg);
    k_blksum  <<<nb, 1024, 0, stream>>>(deg, n, part);
    k_scanpart<<<1, 128, 0, stream>>>(part, nb, rowoff, n);
    k_scanblk <<<nb, 1024, 0, stream>>>(deg, part, n, rowoff);
    k_scatter <<<(e + 255) / 256, 256, 0, stream>>>(ei, ea, e, n, modep, deg, colw);

    k_prep_w1<<<N_HID, 64, 0, stream>>>(fc1w, ln1g, ln1b, fc1b, modep + 1, Wp, u, v);
    k_cvt4   <<<(49152 + 255) / 256, 256, 0, stream>>>(c1rel, c1roo, c2rel, c2roo, modep + 1, cw);

    k_gemm1_mfma<<<(n + 127) / 128, 256, 0, stream>>>(x, modep + 1, Wp, u, v, h1, n);

    k_agg<<<(n + 3) / 4, 256, 0, stream>>>(rowoff, colw, h1, agg1, n, e);
    k_conv1_mfma<<<(n + 127) / 128, 256, 0, stream>>>(agg1, h1, cw, cw + 16384, c1bre, modep + 1, g1, n);

    k_agg<<<(n + 3) / 4, 256, 0, stream>>>(rowoff, colw, g1, agg2, n, e);
    k_conv2_final<<<(n + 127) / 128, 256, 0, stream>>>(agg2, g1, cw + 32768, cw + 40960, c2bre,
                                                       ln2g, ln2b, fc2w, fc2b, modep + 1, d_out, n);
}